// Round 4
// baseline (1381.644 us; speedup 1.0000x reference)
//
#include <hip/hip_runtime.h>
#include <math.h>

#define B_ 128
#define V_ 32
#define D_ 64
#define H_ 256
#define E_ 992
#define ME (B_*E_)   // 126976
#define MV (B_*V_)   // 4096

typedef __attribute__((ext_vector_type(8))) short bf8v;       // 8 bf16 fragment
typedef __attribute__((ext_vector_type(4))) float f4v;        // MFMA accumulator
typedef __attribute__((ext_vector_type(8))) unsigned short u16x8;

__device__ __forceinline__ unsigned short f2bf(float f) {
    union { float f; unsigned int u; } v; v.f = f;
    unsigned int u = v.u + 0x7FFFu + ((v.u >> 16) & 1u);   // RNE
    return (unsigned short)(u >> 16);
}
__device__ __forceinline__ float bf2f(unsigned short h) {
    union { unsigned int u; float f; } v; v.u = ((unsigned int)h) << 16;
    return v.f;
}
__device__ __forceinline__ float sigf(float x) {
    x = fminf(fmaxf(x, -30.f), 30.f);
    return 1.f / (1.f + __expf(-x));
}
__device__ __forceinline__ float tanhf_fast(float x) {
    x = fminf(fmaxf(x, -15.f), 15.f);
    float e = __expf(2.f * x);
    return (e - 1.f) / (e + 1.f);
}
__device__ __forceinline__ void gl_lds16(const unsigned short* g, unsigned short* l) {
    __builtin_amdgcn_global_load_lds(
        (const __attribute__((address_space(1))) unsigned int*)g,
        (__attribute__((address_space(3))) unsigned int*)l, 16, 0, 0);
}

// T-tile swizzle: elem index for (row, k): k-granule XOR'd by row&7 (2-way banks)
__device__ __forceinline__ int tidx(int row, int k) {
    return row * 256 + (k ^ ((row & 7) << 3));
}

// ---------------------------------------------------------------------------
// fp32 -> bf16 conversion kernels
// ---------------------------------------------------------------------------
__global__ __launch_bounds__(256)
void f2b_k(const float* __restrict__ s, unsigned short* __restrict__ d, int n4)
{
    const int g = blockIdx.x * 256 + threadIdx.x;
    if (g >= n4) return;
    const float4 v = ((const float4*)s)[g];
    ushort4 o;
    o.x = f2bf(v.x); o.y = f2bf(v.y); o.z = f2bf(v.z); o.w = f2bf(v.w);
    ((ushort4*)d)[g] = o;
}

__global__ __launch_bounds__(256)
void f2bs_k(const float* __restrict__ s, unsigned short* __restrict__ d,
            int rows, int cols4, int ld, int off)
{
    const int g = blockIdx.x * 256 + threadIdx.x;
    if (g >= rows * cols4) return;
    const int r = g / cols4, c4 = g - r * cols4;
    const float4 v = *(const float4*)(s + (size_t)r * ld + off + c4 * 4);
    ushort4 o;
    o.x = f2bf(v.x); o.y = f2bf(v.y); o.z = f2bf(v.z); o.w = f2bf(v.w);
    *(ushort4*)(d + (size_t)r * cols4 * 4 + c4 * 4) = o;
}

// ---------------------------------------------------------------------------
// fp32 VALU GEMM (node path, small M=4096)
// ---------------------------------------------------------------------------
__global__ __launch_bounds__(256)
void gemm_k(const float* __restrict__ A, int lda,
            const float* __restrict__ W, int ldw,
            const float* __restrict__ bias,
            float* __restrict__ out,
            int M, int N, int K, int do_relu)
{
    __shared__ float As[32][68];
    __shared__ float Ws[32][68];
    const int m0 = blockIdx.x * 64;
    const int n0 = blockIdx.y * 64;
    const int t  = threadIdx.x;
    const int tx = t & 15, ty = t >> 4;
    const int lm = t >> 3;
    const int lk = (t & 7) * 4;

    float acc[4][4] = {};

    for (int k0 = 0; k0 < K; k0 += 32) {
        #pragma unroll
        for (int h = 0; h < 2; ++h) {
            const int m = m0 + lm + h * 32;
            const float4 v = *(const float4*)(A + (size_t)m * lda + k0 + lk);
            As[lk + 0][lm + h * 32] = v.x;
            As[lk + 1][lm + h * 32] = v.y;
            As[lk + 2][lm + h * 32] = v.z;
            As[lk + 3][lm + h * 32] = v.w;
            const int n = n0 + lm + h * 32;
            const float4 w = *(const float4*)(W + (size_t)n * ldw + k0 + lk);
            Ws[lk + 0][lm + h * 32] = w.x;
            Ws[lk + 1][lm + h * 32] = w.y;
            Ws[lk + 2][lm + h * 32] = w.z;
            Ws[lk + 3][lm + h * 32] = w.w;
        }
        __syncthreads();
        #pragma unroll
        for (int kk = 0; kk < 32; ++kk) {
            float a[4], b[4];
            #pragma unroll
            for (int i = 0; i < 4; ++i) a[i] = As[kk][ty * 4 + i];
            #pragma unroll
            for (int j = 0; j < 4; ++j) b[j] = Ws[kk][tx * 4 + j];
            #pragma unroll
            for (int i = 0; i < 4; ++i)
                #pragma unroll
                for (int j = 0; j < 4; ++j)
                    acc[i][j] = fmaf(a[i], b[j], acc[i][j]);
        }
        __syncthreads();
    }

    #pragma unroll
    for (int i = 0; i < 4; ++i) {
        const int m = m0 + ty * 4 + i;
        const size_t ob = (size_t)m * N;
        #pragma unroll
        for (int j = 0; j < 4; ++j) {
            const int n = n0 + tx * 4 + j;
            float v = acc[i][j];
            if (bias) v += bias[n];
            if (do_relu) v = fmaxf(v, 0.f);
            out[ob + n] = v;
        }
    }
}

// ---------------------------------------------------------------------------
// In-LDS GEMM layer: T[128,256] (swizzled, bf16) = act(T @ W.T + bias [+gather])
// In-place safe: all K consumed (barrier) before epilogue writes.
// W streamed via global_load_lds, k-major LDS layout (kpg*2048 + n*8).
// 512 threads, 8 waves (2 row x 4 col), wave tile 64x64, acc 4x4 f4v.
// ---------------------------------------------------------------------------
template<int RELU, int EPI>
__device__ __forceinline__ void chain_gemm(
    unsigned short* T, unsigned short* Wst,
    const unsigned short* __restrict__ W, const float* __restrict__ bias,
    int m0, const float* __restrict__ ES, const float* __restrict__ ER)
{
    const int t = threadIdx.x, lane = t & 63, wid = t >> 6;
    const int r = wid >> 2, c = wid & 3;
    const int kof = (lane >> 4) * 8;
    const int ra = r * 64 + (lane & 15);
    const int q1 = t & 255, kp1 = t >> 8;

    f4v acc[4][4];
    #pragma unroll
    for (int i = 0; i < 4; ++i)
        #pragma unroll
        for (int j = 0; j < 4; ++j)
            acc[i][j] = (f4v){0.f, 0.f, 0.f, 0.f};

    gl_lds16(W + (size_t)q1 * 256 + kp1 * 8,       Wst + t * 8);
    gl_lds16(W + (size_t)q1 * 256 + (kp1 + 2) * 8, Wst + 4096 + t * 8);
    __syncthreads();
    int cur = 0;
    #pragma unroll
    for (int s = 0; s < 8; ++s) {
        if (s < 7) {
            const int k0 = (s + 1) * 32;
            gl_lds16(W + (size_t)q1 * 256 + k0 + kp1 * 8,       Wst + (cur ^ 1) * 8192 + t * 8);
            gl_lds16(W + (size_t)q1 * 256 + k0 + (kp1 + 2) * 8, Wst + (cur ^ 1) * 8192 + 4096 + t * 8);
        }
        bf8v a[4], b[4];
        #pragma unroll
        for (int f = 0; f < 4; ++f) {
            const int rr = ra + f * 16;
            a[f] = *(const bf8v*)&T[tidx(rr, s * 32 + kof)];
            b[f] = *(const bf8v*)&Wst[cur * 8192 + (lane >> 4) * 2048 + (c * 64 + f * 16 + (lane & 15)) * 8];
        }
        #pragma unroll
        for (int i = 0; i < 4; ++i)
            #pragma unroll
            for (int j = 0; j < 4; ++j)
                acc[i][j] = __builtin_amdgcn_mfma_f32_16x16x32_bf16(a[i], b[j], acc[i][j], 0, 0, 0);
        __syncthreads();
        cur ^= 1;
    }

    float bv[4];
    #pragma unroll
    for (int nf = 0; nf < 4; ++nf) bv[nf] = bias[c * 64 + nf * 16 + (lane & 15)];

    #pragma unroll
    for (int mf = 0; mf < 4; ++mf) {
        #pragma unroll
        for (int reg = 0; reg < 4; ++reg) {
            const int row = r * 64 + mf * 16 + (lane >> 4) * 4 + reg;
            size_t bs = 0, br = 0;
            if (EPI) {
                const int m  = m0 + row;
                const int bb = m / E_;
                const int e  = m - bb * E_;
                const int sS = e / 31;
                const int jj = e - sS * 31;
                const int rr = jj + (jj >= sS ? 1 : 0);
                bs = ((size_t)bb * V_ + sS) * H_;
                br = ((size_t)bb * V_ + rr) * H_;
            }
            #pragma unroll
            for (int nf = 0; nf < 4; ++nf) {
                const int n = c * 64 + nf * 16 + (lane & 15);
                float v = acc[mf][nf][reg] + bv[nf];
                if (EPI) v += ES[bs + n] + ER[br + n];
                if (RELU) v = fmaxf(v, 0.f);
                T[tidx(row, n)] = f2bf(v);
            }
        }
    }
    __syncthreads();
}

// ---------------------------------------------------------------------------
// chain1: build A0 = relu(Ys[send]+Yr[recv]+b) in LDS, x2 GEMM, export X2.
// ---------------------------------------------------------------------------
__global__ __launch_bounds__(512, 2)
void chain1_k(const float* __restrict__ Ys, const float* __restrict__ Yr,
              const float* __restrict__ b1,
              const unsigned short* __restrict__ w2, const float* __restrict__ b2,
              const unsigned short* __restrict__ w3, const float* __restrict__ b3,
              unsigned short* __restrict__ X2out)
{
    __shared__ alignas(16) unsigned short T[32768];     // 64KB
    __shared__ alignas(16) unsigned short Wst[16384];   // 32KB
    const int t  = threadIdx.x;
    const int m0 = blockIdx.x * 128;

    #pragma unroll
    for (int it = 0; it < 16; ++it) {
        const int q   = it * 512 + t;
        const int row = q >> 6;
        const int n4  = (q & 63) * 4;
        const int m  = m0 + row;
        const int bb = m / E_;
        const int e  = m - bb * E_;
        const int s  = e / 31;
        const int jj = e - s * 31;
        const int rv = jj + (jj >= s ? 1 : 0);
        const float4 ys = *(const float4*)&Ys[((size_t)bb * V_ + s)  * H_ + n4];
        const float4 yr = *(const float4*)&Yr[((size_t)bb * V_ + rv) * H_ + n4];
        const float4 bx = *(const float4*)&b1[n4];
        ushort4 o;
        o.x = f2bf(fmaxf(ys.x + yr.x + bx.x, 0.f));
        o.y = f2bf(fmaxf(ys.y + yr.y + bx.y, 0.f));
        o.z = f2bf(fmaxf(ys.z + yr.z + bx.z, 0.f));
        o.w = f2bf(fmaxf(ys.w + yr.w + bx.w, 0.f));
        *(ushort4*)&T[tidx(row, n4)] = o;
    }
    __syncthreads();

    chain_gemm<1, 0>(T, Wst, w2, b2, m0, nullptr, nullptr);
    chain_gemm<0, 0>(T, Wst, w3, b3, m0, nullptr, nullptr);

    #pragma unroll
    for (int it = 0; it < 8; ++it) {
        const int g   = it * 512 + t;
        const int row = g >> 5;
        const int kp  = (g & 31) * 8;
        *(u16x8*)&X2out[(size_t)(m0 + row) * 256 + kp] = *(const u16x8*)&T[tidx(row, kp)];
    }
}

// ---------------------------------------------------------------------------
// LSTM pass (one jc of 4): 64 j-cols x 4 gates over K=512 (x4 in T, h0 staged)
// ---------------------------------------------------------------------------
__device__ __forceinline__ void lstm_pass(
    const unsigned short* T, unsigned short* Wst, unsigned short* Ast,
    const unsigned short* __restrict__ h0b,
    const unsigned short* __restrict__ wih, const unsigned short* __restrict__ whh,
    const float* __restrict__ bih, const float* __restrict__ bhh,
    const float* __restrict__ c0,
    float* __restrict__ h1, float* __restrict__ c1, unsigned short* __restrict__ h1b,
    int m0, int jc)
{
    const int t = threadIdx.x, lane = t & 63, wid = t >> 6;
    const int r = wid >> 2, c = wid & 3;
    const int kof = (lane >> 4) * 8;
    const int ra = r * 64 + (lane & 15);
    const int q1 = t & 255, kp1 = t >> 8;
    const size_t grow = (size_t)((q1 >> 6) * 256 + jc * 64 + (q1 & 63)) * 256;
    const int qa = t & 127, kpa = t >> 7;

    f4v acc[4][4];
    #pragma unroll
    for (int i = 0; i < 4; ++i)
        #pragma unroll
        for (int j = 0; j < 4; ++j)
            acc[i][j] = (f4v){0.f, 0.f, 0.f, 0.f};

    gl_lds16(wih + grow + kp1 * 8,       Wst + t * 8);
    gl_lds16(wih + grow + (kp1 + 2) * 8, Wst + 4096 + t * 8);
    __syncthreads();
    int cur = 0;
    #pragma unroll
    for (int s = 0; s < 16; ++s) {
        if (s < 15) {
            const int s2 = s + 1;
            const unsigned short* Wm = (s2 < 8) ? wih : whh;
            const int k0 = (s2 & 7) * 32;
            gl_lds16(Wm + grow + k0 + kp1 * 8,       Wst + (cur ^ 1) * 8192 + t * 8);
            gl_lds16(Wm + grow + k0 + (kp1 + 2) * 8, Wst + (cur ^ 1) * 8192 + 4096 + t * 8);
            if (s2 >= 8) {
                const int ka = (s2 - 8) * 32;
                gl_lds16(h0b + (size_t)(m0 + qa) * 256 + ka + kpa * 8, Ast + (cur ^ 1) * 4096 + t * 8);
            }
        }
        bf8v a[4], b[4];
        #pragma unroll
        for (int f = 0; f < 4; ++f) {
            const int rr = ra + f * 16;
            if (s < 8) a[f] = *(const bf8v*)&T[tidx(rr, s * 32 + kof)];
            else       a[f] = *(const bf8v*)&Ast[cur * 4096 + (lane >> 4) * 1024 + rr * 8];
            b[f] = *(const bf8v*)&Wst[cur * 8192 + (lane >> 4) * 2048 + (f * 64 + c * 16 + (lane & 15)) * 8];
        }
        #pragma unroll
        for (int i = 0; i < 4; ++i)
            #pragma unroll
            for (int g = 0; g < 4; ++g)
                acc[i][g] = __builtin_amdgcn_mfma_f32_16x16x32_bf16(a[i], b[g], acc[i][g], 0, 0, 0);
        __syncthreads();
        cur ^= 1;
    }

    const int j = jc * 64 + c * 16 + (lane & 15);
    const float bi0 = bih[j]       + bhh[j];
    const float bi1 = bih[256 + j] + bhh[256 + j];
    const float bi2 = bih[512 + j] + bhh[512 + j];
    const float bi3 = bih[768 + j] + bhh[768 + j];
    #pragma unroll
    for (int mf = 0; mf < 4; ++mf) {
        #pragma unroll
        for (int reg = 0; reg < 4; ++reg) {
            const int row = r * 64 + mf * 16 + (lane >> 4) * 4 + reg;
            const size_t o = (size_t)(m0 + row) * 256 + j;
            const float gi = acc[mf][0][reg] + bi0;
            const float gf = acc[mf][1][reg] + bi1;
            const float gg = acc[mf][2][reg] + bi2;
            const float go = acc[mf][3][reg] + bi3;
            const float cn = sigf(gf) * c0[o] + sigf(gi) * tanhf_fast(gg);
            const float hn = sigf(go) * tanhf_fast(cn);
            c1[o] = cn;
            h1[o] = hn;
            h1b[o] = f2bf(hn);
        }
    }
    __syncthreads();
}

// ---------------------------------------------------------------------------
// chain2: MLP4 (3 layers, L1 with Zs/Zr gather) + fused LSTM, all per-block.
// ---------------------------------------------------------------------------
__global__ __launch_bounds__(512, 2)
void chain2_k(const unsigned short* __restrict__ X2,
              const unsigned short* __restrict__ w41, const float* __restrict__ b41,
              const unsigned short* __restrict__ w42, const float* __restrict__ b42,
              const unsigned short* __restrict__ w43, const float* __restrict__ b43,
              const float* __restrict__ ZS, const float* __restrict__ ZR,
              const unsigned short* __restrict__ h0b,
              const unsigned short* __restrict__ wih, const unsigned short* __restrict__ whh,
              const float* __restrict__ bih, const float* __restrict__ bhh,
              const float* __restrict__ c0,
              float* __restrict__ h1, float* __restrict__ c1,
              unsigned short* __restrict__ h1b)
{
    __shared__ alignas(16) unsigned short T[32768];     // 64KB
    __shared__ alignas(16) unsigned short Wst[16384];   // 32KB
    __shared__ alignas(16) unsigned short Ast[8192];    // 16KB
    const int t  = threadIdx.x;
    const int m0 = blockIdx.x * 128;

    #pragma unroll
    for (int it = 0; it < 8; ++it) {
        const int g   = it * 512 + t;
        const int row = g >> 5;
        const int kp  = (g & 31) * 8;
        *(u16x8*)&T[tidx(row, kp)] = *(const u16x8*)&X2[(size_t)(m0 + row) * 256 + kp];
    }
    __syncthreads();

    chain_gemm<1, 1>(T, Wst, w41, b41, m0, ZS, ZR);
    chain_gemm<1, 0>(T, Wst, w42, b42, m0, nullptr, nullptr);
    chain_gemm<0, 0>(T, Wst, w43, b43, m0, nullptr, nullptr);

    for (int jc = 0; jc < 4; ++jc)
        lstm_pass(T, Wst, Ast, h0b, wih, whh, bih, bhh, c0, h1, c1, h1b, m0, jc);
}

// ---------------------------------------------------------------------------
// prior chain: h1b -> pw1 -> pw2 -> pw3 (2 cols) fully fused.
// ---------------------------------------------------------------------------
__global__ __launch_bounds__(512, 2)
void prior_k(const unsigned short* __restrict__ Hin,
             const unsigned short* __restrict__ w1, const float* __restrict__ b1,
             const unsigned short* __restrict__ w2, const float* __restrict__ b2,
             const float* __restrict__ w3, const float* __restrict__ b3,
             float* __restrict__ out)
{
    __shared__ alignas(16) unsigned short T[32768];
    __shared__ alignas(16) unsigned short Wst[16384];
    const int t  = threadIdx.x;
    const int m0 = blockIdx.x * 128;

    #pragma unroll
    for (int it = 0; it < 8; ++it) {
        const int g   = it * 512 + t;
        const int row = g >> 5;
        const int kp  = (g & 31) * 8;
        *(u16x8*)&T[tidx(row, kp)] = *(const u16x8*)&Hin[(size_t)(m0 + row) * 256 + kp];
    }
    __syncthreads();

    chain_gemm<1, 0>(T, Wst, w1, b1, m0, nullptr, nullptr);
    chain_gemm<1, 0>(T, Wst, w2, b2, m0, nullptr, nullptr);

    // final 2-col layer: 4 threads per row, 64 k each
    const int row = t >> 2;
    const int kb  = (t & 3) * 64;
    float p0 = 0.f, p1 = 0.f;
    #pragma unroll
    for (int g = 0; g < 8; ++g) {
        const int k = kb + g * 8;
        const u16x8 v = *(const u16x8*)&T[tidx(row, k)];
        #pragma unroll
        for (int i = 0; i < 8; ++i) {
            const float x = bf2f(v[i]);
            p0 += x * w3[k + i];
            p1 += x * w3[256 + k + i];
        }
    }
    p0 += __shfl_xor(p0, 1); p0 += __shfl_xor(p0, 2);
    p1 += __shfl_xor(p1, 1); p1 += __shfl_xor(p1, 2);
    if ((t & 3) == 0) {
        out[(size_t)(m0 + row) * 2 + 0] = p0 + b3[0];
        out[(size_t)(m0 + row) * 2 + 1] = p1 + b3[1];
    }
}

// ---------------------------------------------------------------------------
// edge->node aggregation (bf16 in, fp32 out)
// ---------------------------------------------------------------------------
__global__ __launch_bounds__(256)
void agg_k(const unsigned short* __restrict__ X2, float* __restrict__ outv)
{
    const int g = blockIdx.x * 256 + threadIdx.x;   // over MV*H
    const int h = g & 255;
    const int v = (g >> 8) & 31;
    const int b = g >> 13;
    float s = 0.f;
    #pragma unroll
    for (int snd = 0; snd < 32; ++snd) {
        if (snd == v) continue;
        const int e = snd * 31 + v - (snd < v ? 1 : 0);
        s += bf2f(X2[((size_t)b * E_ + e) * H_ + h]);
    }
    outv[g] = s * (1.f / 31.f);
}

// ---------------------------------------------------------------------------
extern "C" void kernel_launch(void* const* d_in, const int* in_sizes, int n_in,
                              void* d_out, int out_size, void* d_ws, size_t ws_size,
                              hipStream_t stream)
{
    const float* inputs = (const float*)d_in[0];
    const float* h0     = (const float*)d_in[1];
    const float* c0     = (const float*)d_in[2];
    const float* m1w1 = (const float*)d_in[3];  const float* m1b1 = (const float*)d_in[4];
    const float* m1w2 = (const float*)d_in[5];  const float* m1b2 = (const float*)d_in[6];
    const float* m1w3 = (const float*)d_in[7];  const float* m1b3 = (const float*)d_in[8];
    const float* m2w1 = (const float*)d_in[9];  const float* m2b1 = (const float*)d_in[10];
    const float* m2w2 = (const float*)d_in[11]; const float* m2b2 = (const float*)d_in[12];
    const float* m2w3 = (const float*)d_in[13]; const float* m2b3 = (const float*)d_in[14];
    const float* m3w1 = (const float*)d_in[15]; const float* m3b1 = (const float*)d_in[16];
    const float* m3w2 = (const float*)d_in[17]; const float* m3b2 = (const float*)d_in[18];
    const float* m3w3 = (const float*)d_in[19]; const float* m3b3 = (const float*)d_in[20];
    const float* m4w1 = (const float*)d_in[21]; const float* m4b1 = (const float*)d_in[22];
    const float* m4w2 = (const float*)d_in[23]; const float* m4b2 = (const float*)d_in[24];
    const float* m4w3 = (const float*)d_in[25]; const float* m4b3 = (const float*)d_in[26];
    const float* wih  = (const float*)d_in[27]; const float* whh  = (const float*)d_in[28];
    const float* bih  = (const float*)d_in[29]; const float* bhh  = (const float*)d_in[30];
    const float* pw1  = (const float*)d_in[31]; const float* pb1  = (const float*)d_in[32];
    const float* pw2  = (const float*)d_in[33]; const float* pb2  = (const float*)d_in[34];
    const float* pw3  = (const float*)d_in[35]; const float* pb3  = (const float*)d_in[36];

    float* out   = (float*)d_out;
    float* prior = out;
    float* h1    = out + (size_t)ME * 2;
    float* c1    = h1 + (size_t)ME * H_;

    // workspace layout
    float* S0 = (float*)d_ws;                 // 4 node fp32 buffers [MV,256]
    float* S1 = S0 + (size_t)MV * H_;
    float* S2 = S1 + (size_t)MV * H_;
    float* S3 = S2 + (size_t)MV * H_;
    unsigned short* EA = (unsigned short*)(S3 + (size_t)MV * H_);  // X2 bf16 [ME,256]
    unsigned short* EB = EA + (size_t)ME * H_;                     // h0 bf16
    unsigned short* EC = EB + (size_t)ME * H_;                     // h1 bf16
    unsigned short* cw22 = EC + (size_t)ME * H_;   // bf16 weights
    unsigned short* cw23 = cw22 + 65536;
    unsigned short* cw41 = cw23 + 65536;           // m4w1[:,512:768] compacted
    unsigned short* cw42 = cw41 + 65536;
    unsigned short* cw43 = cw42 + 65536;
    unsigned short* cpw1 = cw43 + 65536;
    unsigned short* cpw2 = cpw1 + 65536;
    unsigned short* cwih = cpw2 + 65536;
    unsigned short* cwhh = cwih + 262144;

    const dim3 blk(256);
    const dim3 blk5(512);
    const dim3 gV(MV / 64, 4);      // node fp32 GEMMs
    const dim3 gC(ME / 128);        // fused edge chains (992 blocks)

    // weight + h0 conversions
    f2b_k<<<64, blk, 0, stream>>>(m2w2, cw22, 16384);
    f2b_k<<<64, blk, 0, stream>>>(m2w3, cw23, 16384);
    f2bs_k<<<64, blk, 0, stream>>>(m4w1, cw41, 256, 64, 768, 512);
    f2b_k<<<64, blk, 0, stream>>>(m4w2, cw42, 16384);
    f2b_k<<<64, blk, 0, stream>>>(m4w3, cw43, 16384);
    f2b_k<<<64, blk, 0, stream>>>(pw1, cpw1, 16384);
    f2b_k<<<64, blk, 0, stream>>>(pw2, cpw2, 16384);
    f2b_k<<<256, blk, 0, stream>>>(wih, cwih, 65536);
    f2b_k<<<256, blk, 0, stream>>>(whh, cwhh, 65536);
    f2b_k<<<ME * H_ / 1024, blk, 0, stream>>>(h0, EB, ME * H_ / 4);   // h0 -> bf16

    // MLP1 (node, fp32): inputs -> S0 -> S1 -> S0 (=X1)
    gemm_k<<<gV, blk, 0, stream>>>(inputs, 64, m1w1, 64, m1b1, S0, MV, 256, 64, 1);
    gemm_k<<<gV, blk, 0, stream>>>(S0, 256, m1w2, 256, m1b2, S1, MV, 256, 256, 1);
    gemm_k<<<gV, blk, 0, stream>>>(S1, 256, m1w3, 256, m1b3, S0, MV, 256, 256, 0);

    // Ys / Yr projections (node, fp32)
    gemm_k<<<gV, blk, 0, stream>>>(S0, 256, m2w1,       512, nullptr, S2, MV, 256, 256, 0);
    gemm_k<<<gV, blk, 0, stream>>>(S0, 256, m2w1 + 256, 512, nullptr, S3, MV, 256, 256, 0);

    // fused MLP2 chain -> X2 (EA)
    chain1_k<<<gC, blk5, 0, stream>>>(S2, S3, m2b1, cw22, m2b2, cw23, m2b3, EA);

    // aggregate -> S0 ; MLP3 (node, fp32) -> S1 (=X3)
    agg_k<<<MV * H_ / 256, blk, 0, stream>>>(EA, S0);
    gemm_k<<<gV, blk, 0, stream>>>(S0, 256, m3w1, 256, m3b1, S1, MV, 256, 256, 1);
    gemm_k<<<gV, blk, 0, stream>>>(S1, 256, m3w2, 256, m3b2, S0, MV, 256, 256, 1);
    gemm_k<<<gV, blk, 0, stream>>>(S0, 256, m3w3, 256, m3b3, S1, MV, 256, 256, 0);

    // Zs / Zr projections (node, fp32)
    gemm_k<<<gV, blk, 0, stream>>>(S1, 256, m4w1,       768, nullptr, S2, MV, 256, 256, 0);
    gemm_k<<<gV, blk, 0, stream>>>(S1, 256, m4w1 + 256, 768, nullptr, S3, MV, 256, 256, 0);

    // fused MLP4 + LSTM chain: h1,c1 -> d_out, h1 bf16 -> EC
    chain2_k<<<gC, blk5, 0, stream>>>(EA, cw41, m4b1, cw42, m4b2, cw43, m4b3,
                                      S2, S3, EB, cwih, cwhh, bih, bhh, c0, h1, c1, EC);

    // fused prior chain -> prior
    prior_k<<<gC, blk5, 0, stream>>>(EC, cpw1, pb1, cpw2, pb2, pw3, pb3, prior);
}